// Round 9
// baseline (338.509 us; speedup 1.0000x reference)
//
#include <hip/hip_runtime.h>
#include <hip/hip_bf16.h>
#include <stdint.h>

// ---------------------------------------------------------------------------
// LSTM cell, fused as one bf16 MFMA GEMM:
//   A  = [input | hidden]            : [16384][2048]  (bf16, packed in ws)
//   W  = [Wx[g] | Wh[g]] per gate g  : [4096][2048]   (bf16, packed in ws, [N][K])
//   pre[g][b][s] = sum_k A[b][k] * W[g*1024+s][k] + bias[g][s]
//
// Round 9: deep pipeline. r6/r7/r8 all ~290-310us: per-CU arithmetic shows
// ~5700cyc/K-tile vs ~620cyc MFMA -- stalls. r8's ring gave loads only 1-3
// phases (~450cyc) of slack < HBM latency (~900cyc), so every counted vmcnt
// still stalled, x8 barriers/tile.
//   * BK=32 -> tile = 32KB (A 16KB + W 16KB) -> 4-deep LDS ring (128KB),
//     stage 2 tiles ahead => slack ~2 tiles >> HBM latency.
//   * ONE barrier + ONE vmcnt(6) per tile (12 in flight max; tail peeled
//     at vmcnt(4)/vmcnt(0)). Buffer overwritten by staging was last read
//     2 barriers ago -> WAR safe without per-phase barriers.
//   * No swizzle needed: a 1KB chunk = 16 rows x 32k, and each
//     ds_read_b128 fragment (16 rows x 4 k-slots) = exactly one chunk =
//     bijection onto its 64 16B slots -> banks inherently balanced.
//   * Keep: wave tile 128r x 16s x 4g (acc[4][8]), setprio around MFMA
//     cluster, XCD col-major remap (W L2-resident), fused LSTM epilogue.
// ---------------------------------------------------------------------------

typedef short bf16x8 __attribute__((ext_vector_type(8)));
typedef float f32x4 __attribute__((ext_vector_type(4)));

#define B_ROWS 16384
#define D_K 2048

__device__ __forceinline__ unsigned short f2bf(float f) {
    unsigned u = __builtin_bit_cast(unsigned, f);
    u += 0x7FFFu + ((u >> 16) & 1u);   // round-to-nearest-even
    return (unsigned short)(u >> 16);
}

__device__ __forceinline__ float sigf(float x) { return 1.0f / (1.0f + __expf(-x)); }
__device__ __forceinline__ float tanhfast(float x) { return 2.0f / (1.0f + __expf(-2.0f * x)) - 1.0f; }

// global -> LDS direct copy, 16B per lane; LDS dest wave-uniform base + lane*16.
#define GLD16(gp, lp)                                                          \
    __builtin_amdgcn_global_load_lds(                                          \
        (const __attribute__((address_space(1))) unsigned int*)(gp),           \
        (__attribute__((address_space(3))) unsigned int*)(lp), 16, 0, 0)

#define FENCE() asm volatile("" ::: "memory")

// --------------------------- pack kernels ----------------------------------

__global__ void pack_A_kernel(const float* __restrict__ x,
                              const float* __restrict__ h,
                              unsigned short* __restrict__ A) {
    const int total = B_ROWS * (D_K / 4);          // vec4 units, 512 per row
    for (int v = blockIdx.x * blockDim.x + threadIdx.x; v < total;
         v += gridDim.x * blockDim.x) {
        const int b = v >> 9;
        const int k0 = (v & 511) << 2;
        const float* src = (k0 < 1024) ? (x + (size_t)b * 1024 + k0)
                                       : (h + (size_t)b * 1024 + (k0 - 1024));
        float4 f = *(const float4*)src;
        unsigned p0 = (unsigned)f2bf(f.x) | ((unsigned)f2bf(f.y) << 16);
        unsigned p1 = (unsigned)f2bf(f.z) | ((unsigned)f2bf(f.w) << 16);
        uint2 o; o.x = p0; o.y = p1;
        *(uint2*)(A + (size_t)v * 4) = o;
    }
}

__global__ void pack_W_kernel(const float* __restrict__ Wx,
                              const float* __restrict__ Wh,
                              unsigned short* __restrict__ W) {
    const int total = 4096 * (D_K / 4);
    for (int v = blockIdx.x * blockDim.x + threadIdx.x; v < total;
         v += gridDim.x * blockDim.x) {
        const int n = v >> 9;                       // n = g*1024 + s
        const int k0 = (v & 511) << 2;
        const float* src = (k0 < 1024) ? (Wx + (size_t)n * 1024 + k0)
                                       : (Wh + (size_t)n * 1024 + (k0 - 1024));
        float4 f = *(const float4*)src;
        unsigned p0 = (unsigned)f2bf(f.x) | ((unsigned)f2bf(f.y) << 16);
        unsigned p1 = (unsigned)f2bf(f.z) | ((unsigned)f2bf(f.w) << 16);
        uint2 o; o.x = p0; o.y = p1;
        *(uint2*)(W + (size_t)v * 4) = o;
    }
}

__global__ void pack_bias_kernel(const float* __restrict__ bx,
                                 const float* __restrict__ bh,
                                 float* __restrict__ bias) {
    int i = blockIdx.x * blockDim.x + threadIdx.x;
    if (i < 4096) bias[i] = bx[i] + bh[i];
}

// --------------------------- fused GEMM ------------------------------------
// Tile: BM=256 rows, 64 s-cols x 4 gates (256 W rows), BK=32, 64 K-tiles.
// 512 threads = 8 waves 2M x 4N: wave = 128r x 16s x 4g, acc[4][8] f32x4.
// LDS ring: 4 buffers x 32KB; buffer = 32 chunks of 1KB (A: 0..15, W: 16..31);
// chunk = 16 rows x 32 k-elems; lane l holds row l>>2, k-slot l&3.

__global__ __launch_bounds__(512, 2) void lstm_gemm_kernel(
    const unsigned short* __restrict__ A,     // [16384][2048]
    const unsigned short* __restrict__ W,     // [4096][2048]
    const float* __restrict__ bias,           // [4096]
    const float* __restrict__ cell,           // [16384][1024]
    float* __restrict__ out) {                // new_c then h, each [16384][1024]
    __shared__ __align__(16) unsigned short smem[4][16384];   // 128 KB

    // XCD remap, col-tile-major per XCD: per-XCD W set = 2MB-ish, L2-resident.
    const int bid = blockIdx.x;
    const int wgi = (bid & 7) * 128 + (bid >> 3);
    const int brow = (wgi & 63) << 8;         // 64 row stripes of 256
    const int bcol = (wgi >> 6) << 6;         // 16 col tiles of 64 (s in gate)

    const int tid = threadIdx.x;
    const int wid = tid >> 6;                 // 0..7
    const int lane = tid & 63;
    const int wr = wid >> 2;                  // 0..1: rows wr*128..+128
    const int wc = wid & 3;                   // 0..3: s-cols wc*16..+16
    const int lr = lane & 15, lg = lane >> 4;
    const int l16 = lane >> 2;                // row within a 1KB chunk (16 rows)
    const int lk = (lane & 3) << 3;           // k-elem offset (4 slots of 8)

    f32x4 acc[4][8];
#pragma unroll
    for (int g = 0; g < 4; ++g)
#pragma unroll
        for (int m = 0; m < 8; ++m) acc[g][m] = (f32x4){0.f, 0.f, 0.f, 0.f};

    // staging sources: thread stages 4 chunks: c = wid*4+i (A for wid<4, W else)
    const unsigned short* gp[4];
#pragma unroll
    for (int i = 0; i < 4; ++i) {
        const int c = wid * 4 + i;
        if (c < 16) {
            gp[i] = A + (size_t)(brow + c * 16 + l16) * D_K + lk;
        } else {
            const int cw = c - 16;            // 0..15; gate = cw>>2, s-grp = cw&3
            gp[i] = W + (size_t)((cw >> 2) * 1024 + bcol + (cw & 3) * 16 + l16) * D_K + lk;
        }
    }

#define STAGE(buf, kt)                                                         \
    do {                                                                       \
        char* _d = (char*)smem[buf] + (wid * 4) * 1024;                        \
        _Pragma("unroll")                                                      \
        for (int _i = 0; _i < 4; ++_i) GLD16(gp[_i] + (kt), _d + _i * 1024);   \
    } while (0)

#define COMPUTE(buf)                                                           \
    do {                                                                       \
        const unsigned short* _sb = smem[buf];                                 \
        bf16x8 a[8], w[4];                                                     \
        _Pragma("unroll")                                                      \
        for (int m = 0; m < 8; ++m)                                            \
            a[m] = *(const bf16x8*)&_sb[(wr * 8 + m) * 512 + lr * 32 + lg * 8]; \
        _Pragma("unroll")                                                      \
        for (int g = 0; g < 4; ++g)                                            \
            w[g] = *(const bf16x8*)&_sb[8192 + (g * 4 + wc) * 512 + lr * 32 + lg * 8]; \
        __builtin_amdgcn_s_setprio(1);                                         \
        _Pragma("unroll")                                                      \
        for (int g = 0; g < 4; ++g) {                                          \
            _Pragma("unroll")                                                  \
            for (int m = 0; m < 8; ++m)                                        \
                acc[g][m] = __builtin_amdgcn_mfma_f32_16x16x32_bf16(           \
                    a[m], w[g], acc[g][m], 0, 0, 0);                           \
        }                                                                      \
        __builtin_amdgcn_s_setprio(0);                                         \
    } while (0)

    // prologue: stage tiles 0 and 1 (8 loads in flight)
    STAGE(0, 0);
    STAGE(1, 32);

    // main loop: stage t+2, wait tile t (12 in flight -> vmcnt(6)), 1 barrier
    for (int t = 0; t < 62; ++t) {
        STAGE((t + 2) & 3, (t + 2) * 32);
        asm volatile("s_waitcnt vmcnt(6)" ::: "memory");
        __builtin_amdgcn_s_barrier();
        FENCE();
        COMPUTE(t & 3);
        FENCE();
    }
    // t = 62: 8 in flight, need tile 62 done -> vmcnt(4)
    asm volatile("s_waitcnt vmcnt(4)" ::: "memory");
    __builtin_amdgcn_s_barrier();
    FENCE();
    COMPUTE(2);
    FENCE();
    // t = 63
    asm volatile("s_waitcnt vmcnt(0)" ::: "memory");
    __builtin_amdgcn_s_barrier();
    FENCE();
    COMPUTE(3);

#undef STAGE
#undef COMPUTE

    // fused epilogue: C/D layout col = lane&15, row = (lane>>4)*4 + reg
    float bv[4];
#pragma unroll
    for (int g = 0; g < 4; ++g) bv[g] = bias[(g << 10) + bcol + wc * 16 + lr];

    float* outc = out;
    float* outh = out + (size_t)B_ROWS * 1024;
#pragma unroll
    for (int m = 0; m < 8; ++m) {
#pragma unroll
        for (int r = 0; r < 4; ++r) {
            const int b = brow + wr * 128 + m * 16 + lg * 4 + r;
            const size_t idx = (size_t)b * 1024 + bcol + wc * 16 + lr;
            float pf = acc[0][m][r] + bv[0];
            float pi = acc[1][m][r] + bv[1];
            float pc = acc[2][m][r] + bv[2];
            float po = acc[3][m][r] + bv[3];
            float cl = cell[idx];
            float nc = cl * sigf(pf) + sigf(pi) * tanhfast(pc);
            outc[idx] = nc;
            outh[idx] = tanhfast(nc) * sigf(po);
        }
    }
}

// ------------------- fp32 fallback (ws too small; slow but correct) --------

__global__ void lstm_naive_kernel(const float* __restrict__ x,
                                  const float* __restrict__ cell,
                                  const float* __restrict__ h,
                                  const float* __restrict__ Wx,
                                  const float* __restrict__ bx,
                                  const float* __restrict__ Wh,
                                  const float* __restrict__ bh,
                                  float* __restrict__ out) {
    int idx = blockIdx.x * blockDim.x + threadIdx.x;
    if (idx >= B_ROWS * 1024) return;
    int b = idx >> 10, s = idx & 1023;
    const float* xr = x + (size_t)b * 1024;
    const float* hr = h + (size_t)b * 1024;
    float pre[4];
#pragma unroll
    for (int g = 0; g < 4; ++g) {
        float acc = bx[(g << 10) + s] + bh[(g << 10) + s];
        const float* wx = Wx + ((size_t)(g << 10) + s) * 1024;
        const float* wh = Wh + ((size_t)(g << 10) + s) * 1024;
        for (int k = 0; k < 1024; ++k) acc += xr[k] * wx[k] + hr[k] * wh[k];
        pre[g] = acc;
    }
    float nc = cell[idx] * sigf(pre[0]) + sigf(pre[1]) * tanhfast(pre[2]);
    out[idx] = nc;
    out[(size_t)B_ROWS * 1024 + idx] = tanhfast(nc) * sigf(pre[3]);
}

// ---------------------------------------------------------------------------

extern "C" void kernel_launch(void* const* d_in, const int* in_sizes, int n_in,
                              void* d_out, int out_size, void* d_ws, size_t ws_size,
                              hipStream_t stream) {
    const float* x    = (const float*)d_in[0];
    const float* cell = (const float*)d_in[1];
    const float* hid  = (const float*)d_in[2];
    const float* Wx   = (const float*)d_in[3];
    const float* bx   = (const float*)d_in[4];
    const float* Wh   = (const float*)d_in[5];
    const float* bh   = (const float*)d_in[6];
    float* out = (float*)d_out;

    const size_t szA = (size_t)B_ROWS * D_K * 2;    // 64 MB
    const size_t szW = (size_t)4096 * D_K * 2;      // 16 MB
    const size_t szB = 4096 * 4;
    if (ws_size < szA + szW + szB) {
        lstm_naive_kernel<<<(B_ROWS * 1024) / 256, 256, 0, stream>>>(
            x, cell, hid, Wx, bx, Wh, bh, out);
        return;
    }

    unsigned short* Ab = (unsigned short*)d_ws;
    unsigned short* Wb = (unsigned short*)((char*)d_ws + szA);
    float* bias = (float*)((char*)d_ws + szA + szW);

    pack_A_kernel<<<8192, 256, 0, stream>>>(x, hid, Ab);
    pack_W_kernel<<<2048, 256, 0, stream>>>(Wx, Wh, Wb);
    pack_bias_kernel<<<16, 256, 0, stream>>>(bx, bh, bias);

    lstm_gemm_kernel<<<1024, 512, 0, stream>>>(Ab, Wb, bias, cell, out);
}